// Round 18
// baseline (1552.458 us; speedup 1.0000x reference)
//
#include <hip/hip_runtime.h>

#define BB 4
#define NN 4096
#define CC 128
#define DD 131          // 3 + 128
#define NPOINT 1024

// IEEE-exact, non-fusable fp32 ops (intrinsics are immune to -ffp-contract)
__device__ __forceinline__ float fmul_(float a, float b) { return __fmul_rn(a, b); }
__device__ __forceinline__ float fadd_(float a, float b) { return __fadd_rn(a, b); }

// ---------------------------------------------------------------------------
// dist[b][i][j] = fl(fl(aa_i + aa_j) - 2*ab_ij)   (x2 exact, one rounding)
//   ab = ascending-k single-accumulator FMA chain (Eigen gebp order)
//   aa = XLA:CPU VF8-IC4 reduce. VERIFIED bit-exact (rounds 11-17, absmax 0).
// 64x64 tile, 4x4/thread, k-major LDS, two K chunks. Arithmetic order FROZEN.
// ---------------------------------------------------------------------------
__global__ __launch_bounds__(256) void dist_kernel(const float* __restrict__ points,
                                                   const float* __restrict__ features,
                                                   float* __restrict__ dist) {
    __shared__ float As[67][64];
    __shared__ float Bs[67][64];
    __shared__ float s_aai[64];
    __shared__ float s_aaj[64];

    const int b  = blockIdx.z;
    const int i0 = blockIdx.x * 64;
    const int j0 = blockIdx.y * 64;
    const int tid = threadIdx.x;
    const int r = tid & 63, g = tid >> 6;
    const int tx = tid & 15;
    const int ty = tid >> 4;

    for (int k = g; k < 64; k += 4) {
        float av, bv;
        if (k < 3) {
            av = points[((size_t)b * NN + i0 + r) * 3 + k];
            bv = points[((size_t)b * NN + j0 + r) * 3 + k];
        } else {
            const float* frow = features + ((size_t)b * CC + (k - 3)) * NN;
            av = frow[i0 + r];
            bv = frow[j0 + r];
        }
        As[k][r] = av;
        Bs[k][r] = bv;
    }
    __syncthreads();

    float ph[4][8];
    if (tid < 128) {
        const int rr = tid & 63;
        const float (*S)[64] = (tid < 64) ? As : Bs;
#pragma unroll
        for (int j = 0; j < 4; ++j)
#pragma unroll
            for (int l = 0; l < 8; ++l) {
                float x = S[8 * j + l][rr];
                ph[j][l] = fmul_(x, x);                       // it = 0
            }
#pragma unroll
        for (int j = 0; j < 4; ++j)
#pragma unroll
            for (int l = 0; l < 8; ++l) {
                float x = S[32 + 8 * j + l][rr];
                ph[j][l] = fadd_(ph[j][l], fmul_(x, x));      // it = 1
            }
    }

    float acc[4][4];
#pragma unroll
    for (int p = 0; p < 4; ++p)
#pragma unroll
        for (int q = 0; q < 4; ++q) acc[p][q] = 0.f;

#pragma unroll 4
    for (int kk = 0; kk < 64; ++kk) {
        float4 a4 = *(const float4*)&As[kk][4 * ty];
        float4 b4 = *(const float4*)&Bs[kk][4 * tx];
        const float a[4] = {a4.x, a4.y, a4.z, a4.w};
        const float c[4] = {b4.x, b4.y, b4.z, b4.w};
#pragma unroll
        for (int p = 0; p < 4; ++p)
#pragma unroll
            for (int q = 0; q < 4; ++q)
                acc[p][q] = __builtin_fmaf(a[p], c[q], acc[p][q]);
    }
    __syncthreads();

    for (int k = g; k < 67; k += 4) {
        const float* frow = features + ((size_t)b * CC + (64 + k - 3)) * NN;
        As[k][r] = frow[i0 + r];
        Bs[k][r] = frow[j0 + r];
    }
    __syncthreads();

    if (tid < 128) {
        const int rr = tid & 63;
        const float (*S)[64] = (tid < 64) ? As : Bs;
#pragma unroll
        for (int j = 0; j < 4; ++j)
#pragma unroll
            for (int l = 0; l < 8; ++l) {
                float x = S[8 * j + l][rr];
                ph[j][l] = fadd_(ph[j][l], fmul_(x, x));      // it = 2
            }
#pragma unroll
        for (int j = 0; j < 4; ++j)
#pragma unroll
            for (int l = 0; l < 8; ++l) {
                float x = S[32 + 8 * j + l][rr];
                ph[j][l] = fadd_(ph[j][l], fmul_(x, x));      // it = 3
            }
        float v[8];
#pragma unroll
        for (int l = 0; l < 8; ++l)
            v[l] = fadd_(fadd_(fadd_(ph[0][l], ph[1][l]), ph[2][l]), ph[3][l]);
        float h4_0 = fadd_(v[0], v[4]), h4_1 = fadd_(v[1], v[5]);
        float h4_2 = fadd_(v[2], v[6]), h4_3 = fadd_(v[3], v[7]);
        float h1 = fadd_(fadd_(h4_0, h4_2), fadd_(h4_1, h4_3));
        float t0 = S[64][rr], t1 = S[65][rr], t2 = S[66][rr];
        h1 = fadd_(h1, fmul_(t0, t0));
        h1 = fadd_(h1, fmul_(t1, t1));
        h1 = fadd_(h1, fmul_(t2, t2));
        if (tid < 64) s_aai[rr] = h1; else s_aaj[rr] = h1;
    }

#pragma unroll 4
    for (int kk = 0; kk < 67; ++kk) {
        float4 a4 = *(const float4*)&As[kk][4 * ty];
        float4 b4 = *(const float4*)&Bs[kk][4 * tx];
        const float a[4] = {a4.x, a4.y, a4.z, a4.w};
        const float c[4] = {b4.x, b4.y, b4.z, b4.w};
#pragma unroll
        for (int p = 0; p < 4; ++p)
#pragma unroll
            for (int q = 0; q < 4; ++q)
                acc[p][q] = __builtin_fmaf(a[p], c[q], acc[p][q]);
    }
    __syncthreads();

#pragma unroll
    for (int p = 0; p < 4; ++p) {
        const int i = i0 + 4 * ty + p;
        const float aai = s_aai[4 * ty + p];
        float4 o;
        o.x = __builtin_fmaf(-2.0f, acc[p][0], fadd_(aai, s_aaj[4 * tx + 0]));
        o.y = __builtin_fmaf(-2.0f, acc[p][1], fadd_(aai, s_aaj[4 * tx + 1]));
        o.z = __builtin_fmaf(-2.0f, acc[p][2], fadd_(aai, s_aaj[4 * tx + 2]));
        o.w = __builtin_fmaf(-2.0f, acc[p][3], fadd_(aai, s_aaj[4 * tx + 3]));
        *(float4*)&dist[((size_t)b * NN + i) * NN + j0 + 4 * tx] = o;
    }
}

// ---------------------------------------------------------------------------
// DPP wave64 argmax combine (pure VALU, ~5 ops/step; no ds_bpermute).
// ---------------------------------------------------------------------------
template <int CTRL>
__device__ __forceinline__ void dpp_step(float& v, int& i) {
    int ovb = __builtin_amdgcn_update_dpp(0, __float_as_int(v), CTRL, 0xF, 0xF, false);
    int oi  = __builtin_amdgcn_update_dpp(0, i,                 CTRL, 0xF, 0xF, false);
    float ov = __int_as_float(ovb);
    if (ov > v || (ov == v && oi < i)) { v = ov; i = oi; }
}

// monotonic (value, lower-index-wins) packing for cross-wave u64-max keys
__device__ __forceinline__ unsigned long long pack_vi(float v, int idx) {
    unsigned u = __float_as_uint(v);
    u = ((int)u >= 0) ? (u | 0x80000000u) : ~u;
    if (v == 0.0f) u = 0x80000000u;   // normalize -0/+0 (compare equal in np)
    return ((unsigned long long)u << 32) | (unsigned)(4095 - idx);
}

// local (value, index) update, ascending-index order => first-occurrence
__device__ __forceinline__ void upd(float& bv, int& bi, float m, int idx) {
    if (m > bv) { bv = m; bi = idx; }
}

// ---------------------------------------------------------------------------
// Sequential FPS — 512 threads (8 waves) per batch, 8 cols/thread.
// R17 post-mortem: VGPR_Count=20 proved the scheduler SERIALIZED the two
// row loads into two ~1000cyc round trips to minimize register pressure.
// Fix: __builtin_amdgcn_sched_barrier(0) after both loads — nothing may
// cross, so both issue back-to-back => ONE memory round trip per step.
// Reduce: 8-elem scan -> 6 DPP -> readlane(63) -> 8-slot u64 LDS combine
// (parity dbuf, one barrier). History in LDS, flushed once at the end.
// ---------------------------------------------------------------------------
__global__ __launch_bounds__(512, 1) void fps_kernel(const float* __restrict__ dist,
                                                     int* __restrict__ out) {
    const int b = blockIdx.x;
    const int tid = threadIdx.x;
    const int lane = tid & 63;
    const int wave = tid >> 6;
    const float* Dm = dist + (size_t)b * NN * NN;

    __shared__ unsigned long long s_slot[2][8];
    __shared__ int s_hist[NPOINT];

    float4 m0 = make_float4(1e10f, 1e10f, 1e10f, 1e10f), m1 = m0;
    int last = 0;

    for (int k = 0; k < NPOINT; ++k) {
        const float* row = Dm + (size_t)last * NN + 4 * tid;
        float4 d0 = *(const float4*)&row[0];
        float4 d1 = *(const float4*)&row[2048];
        __builtin_amdgcn_sched_barrier(0);   // force both loads in flight

        if (tid == 0) s_hist[k] = last;

        m0.x = fminf(m0.x, d0.x); m0.y = fminf(m0.y, d0.y);
        m0.z = fminf(m0.z, d0.z); m0.w = fminf(m0.w, d0.w);
        m1.x = fminf(m1.x, d1.x); m1.y = fminf(m1.y, d1.y);
        m1.z = fminf(m1.z, d1.z); m1.w = fminf(m1.w, d1.w);

        // linear scan, ascending global index (first-occurrence semantics)
        const int t4 = 4 * tid;
        float bv = m0.x; int bi = t4;
        upd(bv, bi, m0.y, t4 + 1);
        upd(bv, bi, m0.z, t4 + 2);
        upd(bv, bi, m0.w, t4 + 3);
        upd(bv, bi, m1.x, 2048 + t4);
        upd(bv, bi, m1.y, 2048 + t4 + 1);
        upd(bv, bi, m1.z, 2048 + t4 + 2);
        upd(bv, bi, m1.w, 2048 + t4 + 3);

        // wave64 DPP reduction -> lane 63, then uniform via readlane
        dpp_step<0xB1>(bv, bi);    // quad_perm [1,0,3,2]  (xor 1)
        dpp_step<0x4E>(bv, bi);    // quad_perm [2,3,0,1]  (xor 2)
        dpp_step<0x141>(bv, bi);   // row_half_mirror      (xor 4)
        dpp_step<0x140>(bv, bi);   // row_mirror           (xor 8)
        dpp_step<0x142>(bv, bi);   // row_bcast15
        dpp_step<0x143>(bv, bi);   // row_bcast31
        float wv = __int_as_float(__builtin_amdgcn_readlane(__float_as_int(bv), 63));
        int   wi = __builtin_amdgcn_readlane(bi, 63);

        // cross-wave combine (8 slots, parity dbuf, one barrier)
        const int p = k & 1;
        if (lane == 0) s_slot[p][wave] = pack_vi(wv, wi);
        __syncthreads();

        unsigned long long w = s_slot[p][0];
#pragma unroll
        for (int c = 1; c < 8; ++c) {
            unsigned long long s = s_slot[p][c];
            w = (s > w) ? s : w;
        }
        last = 4095 - (int)(unsigned)(w & 0xFFFFFFFFull);
    }
    __syncthreads();

    // flush history: 2 ints per thread, coalesced
    out[b * NPOINT + tid]       = s_hist[tid];
    out[b * NPOINT + 512 + tid] = s_hist[512 + tid];
}

// ---------------------------------------------------------------------------
extern "C" void kernel_launch(void* const* d_in, const int* in_sizes, int n_in,
                              void* d_out, int out_size, void* d_ws, size_t ws_size,
                              hipStream_t stream) {
    const float* points   = (const float*)d_in[0];
    const float* features = (const float*)d_in[1];
    int* out = (int*)d_out;

    float* dist = (float*)d_ws;   // exactly 256 MiB

    dim3 g(NN / 64, NN / 64, BB);
    dist_kernel<<<g, 256, 0, stream>>>(points, features, dist);

    fps_kernel<<<BB, 512, 0, stream>>>(dist, out);
}

// Round 19
// 1500.053 us; speedup vs baseline: 1.0349x; 1.0349x over previous
//
#include <hip/hip_runtime.h>

#define BB 4
#define NN 4096
#define CC 128
#define DD 131          // 3 + 128
#define NPOINT 1024

// IEEE-exact, non-fusable fp32 ops (intrinsics are immune to -ffp-contract)
__device__ __forceinline__ float fmul_(float a, float b) { return __fmul_rn(a, b); }
__device__ __forceinline__ float fadd_(float a, float b) { return __fadd_rn(a, b); }

// ---------------------------------------------------------------------------
// dist[b][i][j] = fl(fl(aa_i + aa_j) - 2*ab_ij)   (x2 exact, one rounding)
//   ab = ascending-k single-accumulator FMA chain (Eigen gebp order)
//   aa = XLA:CPU VF8-IC4 reduce. VERIFIED bit-exact (rounds 11-18, absmax 0).
// 64x64 tile, 4x4/thread, k-major LDS, two K chunks. Arithmetic order FROZEN.
// ---------------------------------------------------------------------------
__global__ __launch_bounds__(256) void dist_kernel(const float* __restrict__ points,
                                                   const float* __restrict__ features,
                                                   float* __restrict__ dist) {
    __shared__ float As[67][64];
    __shared__ float Bs[67][64];
    __shared__ float s_aai[64];
    __shared__ float s_aaj[64];

    const int b  = blockIdx.z;
    const int i0 = blockIdx.x * 64;
    const int j0 = blockIdx.y * 64;
    const int tid = threadIdx.x;
    const int r = tid & 63, g = tid >> 6;
    const int tx = tid & 15;
    const int ty = tid >> 4;

    for (int k = g; k < 64; k += 4) {
        float av, bv;
        if (k < 3) {
            av = points[((size_t)b * NN + i0 + r) * 3 + k];
            bv = points[((size_t)b * NN + j0 + r) * 3 + k];
        } else {
            const float* frow = features + ((size_t)b * CC + (k - 3)) * NN;
            av = frow[i0 + r];
            bv = frow[j0 + r];
        }
        As[k][r] = av;
        Bs[k][r] = bv;
    }
    __syncthreads();

    float ph[4][8];
    if (tid < 128) {
        const int rr = tid & 63;
        const float (*S)[64] = (tid < 64) ? As : Bs;
#pragma unroll
        for (int j = 0; j < 4; ++j)
#pragma unroll
            for (int l = 0; l < 8; ++l) {
                float x = S[8 * j + l][rr];
                ph[j][l] = fmul_(x, x);                       // it = 0
            }
#pragma unroll
        for (int j = 0; j < 4; ++j)
#pragma unroll
            for (int l = 0; l < 8; ++l) {
                float x = S[32 + 8 * j + l][rr];
                ph[j][l] = fadd_(ph[j][l], fmul_(x, x));      // it = 1
            }
    }

    float acc[4][4];
#pragma unroll
    for (int p = 0; p < 4; ++p)
#pragma unroll
        for (int q = 0; q < 4; ++q) acc[p][q] = 0.f;

#pragma unroll 4
    for (int kk = 0; kk < 64; ++kk) {
        float4 a4 = *(const float4*)&As[kk][4 * ty];
        float4 b4 = *(const float4*)&Bs[kk][4 * tx];
        const float a[4] = {a4.x, a4.y, a4.z, a4.w};
        const float c[4] = {b4.x, b4.y, b4.z, b4.w};
#pragma unroll
        for (int p = 0; p < 4; ++p)
#pragma unroll
            for (int q = 0; q < 4; ++q)
                acc[p][q] = __builtin_fmaf(a[p], c[q], acc[p][q]);
    }
    __syncthreads();

    for (int k = g; k < 67; k += 4) {
        const float* frow = features + ((size_t)b * CC + (64 + k - 3)) * NN;
        As[k][r] = frow[i0 + r];
        Bs[k][r] = frow[j0 + r];
    }
    __syncthreads();

    if (tid < 128) {
        const int rr = tid & 63;
        const float (*S)[64] = (tid < 64) ? As : Bs;
#pragma unroll
        for (int j = 0; j < 4; ++j)
#pragma unroll
            for (int l = 0; l < 8; ++l) {
                float x = S[8 * j + l][rr];
                ph[j][l] = fadd_(ph[j][l], fmul_(x, x));      // it = 2
            }
#pragma unroll
        for (int j = 0; j < 4; ++j)
#pragma unroll
            for (int l = 0; l < 8; ++l) {
                float x = S[32 + 8 * j + l][rr];
                ph[j][l] = fadd_(ph[j][l], fmul_(x, x));      // it = 3
            }
        float v[8];
#pragma unroll
        for (int l = 0; l < 8; ++l)
            v[l] = fadd_(fadd_(fadd_(ph[0][l], ph[1][l]), ph[2][l]), ph[3][l]);
        float h4_0 = fadd_(v[0], v[4]), h4_1 = fadd_(v[1], v[5]);
        float h4_2 = fadd_(v[2], v[6]), h4_3 = fadd_(v[3], v[7]);
        float h1 = fadd_(fadd_(h4_0, h4_2), fadd_(h4_1, h4_3));
        float t0 = S[64][rr], t1 = S[65][rr], t2 = S[66][rr];
        h1 = fadd_(h1, fmul_(t0, t0));
        h1 = fadd_(h1, fmul_(t1, t1));
        h1 = fadd_(h1, fmul_(t2, t2));
        if (tid < 64) s_aai[rr] = h1; else s_aaj[rr] = h1;
    }

#pragma unroll 4
    for (int kk = 0; kk < 67; ++kk) {
        float4 a4 = *(const float4*)&As[kk][4 * ty];
        float4 b4 = *(const float4*)&Bs[kk][4 * tx];
        const float a[4] = {a4.x, a4.y, a4.z, a4.w};
        const float c[4] = {b4.x, b4.y, b4.z, b4.w};
#pragma unroll
        for (int p = 0; p < 4; ++p)
#pragma unroll
            for (int q = 0; q < 4; ++q)
                acc[p][q] = __builtin_fmaf(a[p], c[q], acc[p][q]);
    }
    __syncthreads();

#pragma unroll
    for (int p = 0; p < 4; ++p) {
        const int i = i0 + 4 * ty + p;
        const float aai = s_aai[4 * ty + p];
        float4 o;
        o.x = __builtin_fmaf(-2.0f, acc[p][0], fadd_(aai, s_aaj[4 * tx + 0]));
        o.y = __builtin_fmaf(-2.0f, acc[p][1], fadd_(aai, s_aaj[4 * tx + 1]));
        o.z = __builtin_fmaf(-2.0f, acc[p][2], fadd_(aai, s_aaj[4 * tx + 2]));
        o.w = __builtin_fmaf(-2.0f, acc[p][3], fadd_(aai, s_aaj[4 * tx + 3]));
        *(float4*)&dist[((size_t)b * NN + i) * NN + j0 + 4 * tx] = o;
    }
}

// ---------------------------------------------------------------------------
// DPP wave64 argmax combine (pure VALU, ~5 ops/step; no ds_bpermute).
// ---------------------------------------------------------------------------
template <int CTRL>
__device__ __forceinline__ void dpp_step(float& v, int& i) {
    int ovb = __builtin_amdgcn_update_dpp(0, __float_as_int(v), CTRL, 0xF, 0xF, false);
    int oi  = __builtin_amdgcn_update_dpp(0, i,                 CTRL, 0xF, 0xF, false);
    float ov = __int_as_float(ovb);
    if (ov > v || (ov == v && oi < i)) { v = ov; i = oi; }
}

// monotonic (value, lower-index-wins) packing for cross-wave u64-max keys
__device__ __forceinline__ unsigned long long pack_vi(float v, int idx) {
    unsigned u = __float_as_uint(v);
    u = ((int)u >= 0) ? (u | 0x80000000u) : ~u;
    if (v == 0.0f) u = 0x80000000u;   // normalize -0/+0 (compare equal in np)
    return ((unsigned long long)u << 32) | (unsigned)(4095 - idx);
}

// local (value, index) update, ascending-index order => first-occurrence
__device__ __forceinline__ void upd(float& bv, int& bi, float m, int idx) {
    if (m > bv) { bv = m; bi = idx; }
}

// ---------------------------------------------------------------------------
// Sequential FPS — 128 threads (2 waves) per batch, 32 cols/thread:
// {512*c + 4*t + e : c=0..7}. Step budget model (R12-R18 counters): cost =
// n_load_roundtrips * ~1200 + barrier_chain(waves). 8 waves: 1200+1600=2850
// (R17 measured). 2 waves with PARALLEL loads: 1200+~500 => ~1700 cyc.
// R16 failed because its 8 loads serialized into ~3 trips (VGPR=44 proves
// only ~2 live). Fix: sched_barrier(0) AFTER all 8 loads — hard scheduling
// fence, so all 8 must be scheduled (and allocated) before any consumer =>
// one vmcnt drain, one round trip. Confirming signal: VGPR_Count >= ~70.
// Reduce: linear 32-scan (ascending idx) -> 6 DPP -> readlane(63) -> 2-slot
// u64 LDS combine (parity dbuf, one 2-wave barrier). History in LDS.
// ---------------------------------------------------------------------------
__global__ __launch_bounds__(128, 1) void fps_kernel(const float* __restrict__ dist,
                                                     int* __restrict__ out) {
    const int b = blockIdx.x;
    const int tid = threadIdx.x;
    const int lane = tid & 63;
    const int wave = tid >> 6;
    const float* Dm = dist + (size_t)b * NN * NN;

    __shared__ unsigned long long s_slot[2][2];
    __shared__ int s_hist[NPOINT];

    float4 m0 = make_float4(1e10f, 1e10f, 1e10f, 1e10f), m1 = m0, m2 = m0, m3 = m0;
    float4 m4 = m0, m5 = m0, m6 = m0, m7 = m0;
    int last = 0;

    for (int k = 0; k < NPOINT; ++k) {
        const float* row = Dm + (size_t)last * NN + 4 * tid;
        float4 d0 = *(const float4*)&row[0];
        float4 d1 = *(const float4*)&row[512];
        float4 d2 = *(const float4*)&row[1024];
        float4 d3 = *(const float4*)&row[1536];
        float4 d4 = *(const float4*)&row[2048];
        float4 d5 = *(const float4*)&row[2560];
        float4 d6 = *(const float4*)&row[3072];
        float4 d7 = *(const float4*)&row[3584];
        __builtin_amdgcn_sched_barrier(0);   // all 8 loads issue before any use

        if (tid == 0) s_hist[k] = last;

        m0.x = fminf(m0.x, d0.x); m0.y = fminf(m0.y, d0.y);
        m0.z = fminf(m0.z, d0.z); m0.w = fminf(m0.w, d0.w);
        m1.x = fminf(m1.x, d1.x); m1.y = fminf(m1.y, d1.y);
        m1.z = fminf(m1.z, d1.z); m1.w = fminf(m1.w, d1.w);
        m2.x = fminf(m2.x, d2.x); m2.y = fminf(m2.y, d2.y);
        m2.z = fminf(m2.z, d2.z); m2.w = fminf(m2.w, d2.w);
        m3.x = fminf(m3.x, d3.x); m3.y = fminf(m3.y, d3.y);
        m3.z = fminf(m3.z, d3.z); m3.w = fminf(m3.w, d3.w);
        m4.x = fminf(m4.x, d4.x); m4.y = fminf(m4.y, d4.y);
        m4.z = fminf(m4.z, d4.z); m4.w = fminf(m4.w, d4.w);
        m5.x = fminf(m5.x, d5.x); m5.y = fminf(m5.y, d5.y);
        m5.z = fminf(m5.z, d5.z); m5.w = fminf(m5.w, d5.w);
        m6.x = fminf(m6.x, d6.x); m6.y = fminf(m6.y, d6.y);
        m6.z = fminf(m6.z, d6.z); m6.w = fminf(m6.w, d6.w);
        m7.x = fminf(m7.x, d7.x); m7.y = fminf(m7.y, d7.y);
        m7.z = fminf(m7.z, d7.z); m7.w = fminf(m7.w, d7.w);

        // linear scan, ascending global index (first-occurrence semantics)
        const int t4 = 4 * tid;
        float bv = m0.x; int bi = t4;
        upd(bv, bi, m0.y, t4 + 1); upd(bv, bi, m0.z, t4 + 2); upd(bv, bi, m0.w, t4 + 3);
        upd(bv, bi, m1.x, 512 + t4);  upd(bv, bi, m1.y, 512 + t4 + 1);
        upd(bv, bi, m1.z, 512 + t4 + 2); upd(bv, bi, m1.w, 512 + t4 + 3);
        upd(bv, bi, m2.x, 1024 + t4); upd(bv, bi, m2.y, 1024 + t4 + 1);
        upd(bv, bi, m2.z, 1024 + t4 + 2); upd(bv, bi, m2.w, 1024 + t4 + 3);
        upd(bv, bi, m3.x, 1536 + t4); upd(bv, bi, m3.y, 1536 + t4 + 1);
        upd(bv, bi, m3.z, 1536 + t4 + 2); upd(bv, bi, m3.w, 1536 + t4 + 3);
        upd(bv, bi, m4.x, 2048 + t4); upd(bv, bi, m4.y, 2048 + t4 + 1);
        upd(bv, bi, m4.z, 2048 + t4 + 2); upd(bv, bi, m4.w, 2048 + t4 + 3);
        upd(bv, bi, m5.x, 2560 + t4); upd(bv, bi, m5.y, 2560 + t4 + 1);
        upd(bv, bi, m5.z, 2560 + t4 + 2); upd(bv, bi, m5.w, 2560 + t4 + 3);
        upd(bv, bi, m6.x, 3072 + t4); upd(bv, bi, m6.y, 3072 + t4 + 1);
        upd(bv, bi, m6.z, 3072 + t4 + 2); upd(bv, bi, m6.w, 3072 + t4 + 3);
        upd(bv, bi, m7.x, 3584 + t4); upd(bv, bi, m7.y, 3584 + t4 + 1);
        upd(bv, bi, m7.z, 3584 + t4 + 2); upd(bv, bi, m7.w, 3584 + t4 + 3);

        // wave64 DPP reduction -> lane 63, then uniform via readlane
        dpp_step<0xB1>(bv, bi);    // quad_perm [1,0,3,2]  (xor 1)
        dpp_step<0x4E>(bv, bi);    // quad_perm [2,3,0,1]  (xor 2)
        dpp_step<0x141>(bv, bi);   // row_half_mirror      (xor 4)
        dpp_step<0x140>(bv, bi);   // row_mirror           (xor 8)
        dpp_step<0x142>(bv, bi);   // row_bcast15
        dpp_step<0x143>(bv, bi);   // row_bcast31
        float wv = __int_as_float(__builtin_amdgcn_readlane(__float_as_int(bv), 63));
        int   wi = __builtin_amdgcn_readlane(bi, 63);

        // cross-wave combine (2 slots, parity dbuf, one barrier)
        const int p = k & 1;
        if (lane == 0) s_slot[p][wave] = pack_vi(wv, wi);
        __syncthreads();

        unsigned long long s0 = s_slot[p][0], s1 = s_slot[p][1];
        unsigned long long w = (s1 > s0) ? s1 : s0;
        last = 4095 - (int)(unsigned)(w & 0xFFFFFFFFull);
    }
    __syncthreads();

    // flush history: 8 ints per thread, coalesced
#pragma unroll
    for (int c = 0; c < 8; ++c)
        out[b * NPOINT + 128 * c + tid] = s_hist[128 * c + tid];
}

// ---------------------------------------------------------------------------
extern "C" void kernel_launch(void* const* d_in, const int* in_sizes, int n_in,
                              void* d_out, int out_size, void* d_ws, size_t ws_size,
                              hipStream_t stream) {
    const float* points   = (const float*)d_in[0];
    const float* features = (const float*)d_in[1];
    int* out = (int*)d_out;

    float* dist = (float*)d_ws;   // exactly 256 MiB

    dim3 g(NN / 64, NN / 64, BB);
    dist_kernel<<<g, 256, 0, stream>>>(points, features, dist);

    fps_kernel<<<BB, 128, 0, stream>>>(dist, out);
}